// Round 20
// baseline (150.445 us; speedup 1.0000x reference)
//
#include <hip/hip_runtime.h>
#include <hip/hip_bf16.h>
#include <stdint.h>

#define CH   384
#define HID  512
#define NHD  8
#define MTOT 32768   // B*H*W tokens

typedef __attribute__((ext_vector_type(8))) short bf16x8;
typedef __attribute__((ext_vector_type(4))) float f32x4;
typedef unsigned short u16;

__device__ __forceinline__ float bf2f(u16 v){ return __uint_as_float(((unsigned)v)<<16); }
__device__ __forceinline__ u16 f2bf(float f){
  unsigned u = __float_as_uint(f);
  return (u16)((u + 0x7fffu + ((u>>16)&1u)) >> 16);
}
__device__ __forceinline__ float fast_tanh(float s){
  float e = __expf(2.f*s);
  return 1.f - 2.f*__builtin_amdgcn_rcpf(e + 1.f);
}
__device__ __forceinline__ void gload_lds16(const void* g, void* l){
  __builtin_amdgcn_global_load_lds((const __attribute__((address_space(1))) void*)g,
                                   (__attribute__((address_space(3))) void*)l, 16, 0, 0);
}

// ---------------- fp32 -> bf16 convert (W1, W2 only; x fused into gemm1) ----------------
#define CVT_N1 (3*HID*CH/4)       // 147456 float4s
#define CVT_N2 (CH*HID/4)         // 49152
__global__ void k_cvt2(const float* __restrict__ w1, u16* __restrict__ w1o,
                       const float* __restrict__ w2, u16* __restrict__ w2o){
  const int total = CVT_N1 + CVT_N2;
  int i = blockIdx.x*blockDim.x + threadIdx.x;
  int stride = gridDim.x*blockDim.x;
  for (; i < total; i += stride){
    const float4* src; ushort4* dst; int k;
    if (i < CVT_N1){ src = (const float4*)w1; dst = (ushort4*)w1o; k = i; }
    else { src = (const float4*)w2; dst = (ushort4*)w2o; k = i - CVT_N1; }
    float4 v = src[k];
    ushort4 o; o.x=f2bf(v.x); o.y=f2bf(v.y); o.z=f2bf(v.z); o.w=f2bf(v.w);
    dst[k] = o;
  }
}

// ---------------- GEMM1 v12: v8 structure + fused x fp32->bf16 A-staging ----------------
// A register-staged from fp32 x (2x dwordx4 -> 8 f2bf -> ds_write_b128, dest-swizzled);
// B via async gload_lds (issued first, covers A-convert VALU). K-loop/epilogue = v8.
__global__ __launch_bounds__(256)
void k_gemm1(const float* __restrict__ xf, const u16* __restrict__ w1b,
             const float* __restrict__ b1,
             u16* __restrict__ xh, u16* __restrict__ yb)
{
  __shared__ short lds[14336];  // A [0,8192)  B [8192,14336)  (28KB)
  const int tid = threadIdx.x;
  const int w = tid >> 6, lw = tid & 63;
  const int bid = blockIdx.x;
  const int xcd = bid & 7, ii = bid >> 3;
  const int m0 = (xcd*32 + (ii >> 4)) * 128;
  const int h0 = (ii & 15) * 32;
  const int lc = lw & 15, lk = lw >> 4;

  f32x4 acc[2][6] = {};   // [mi][seg*2+f]

  // ---- A staging descriptors: 16 chunks (8 rows x 64 bf16); chunk ca=i*4+w ----
  // thread: row = ca*8 + (lw>>3), source slice sg = lw&7 (natural, coalesced fp32);
  // dest slice = sg ^ (row&7)  ->  LDS[row][t] = G[row][t^(row&7)] (v8 invariant).
  const int arow_sub = lw >> 3;
  const int asl = lw & 7;
  const float* axsrc[4]; int adst[4];
  #pragma unroll
  for (int i = 0; i < 4; ++i){
    int ca = i*4 + w;
    int row = ca*8 + arow_sub;
    axsrc[i] = xf + (size_t)(m0 + row)*CH + asl*8;
    adst[i]  = row*64 + ((asl ^ arow_sub)*8);
  }
  // ---- B staging: 12 chunks async gload_lds, source-swizzled (v8 verbatim math) ----
  const int sl = (lw & 7) ^ (lw >> 3);
  const u16* gsrcB[3]; int ldstB[3];
  #pragma unroll
  for (int i = 0; i < 3; ++i){
    int cb = i*4 + w;                     // 0..11
    int rb = cb*8 + arow_sub;             // 0..95
    int grow = (rb >> 5)*HID + h0 + (rb & 31);
    gsrcB[i] = w1b + (size_t)grow*CH + sl*8;
    ldstB[i] = 8192 + cb*512;
  }

  #pragma unroll 1
  for (int kt = 0; kt < 6; ++kt){
    #pragma unroll
    for (int i = 0; i < 3; ++i)
      gload_lds16(gsrcB[i] + kt*64, &lds[ldstB[i]]);
    #pragma unroll
    for (int i = 0; i < 4; ++i){
      const float* p = axsrc[i] + kt*64;
      float4 f0 = *(const float4*)p;
      float4 f1 = *(const float4*)(p+4);
      bf16x8 o;
      o[0]=(short)f2bf(f0.x); o[1]=(short)f2bf(f0.y); o[2]=(short)f2bf(f0.z); o[3]=(short)f2bf(f0.w);
      o[4]=(short)f2bf(f1.x); o[5]=(short)f2bf(f1.y); o[6]=(short)f2bf(f1.z); o[7]=(short)f2bf(f1.w);
      *(bf16x8*)&lds[adst[i]] = o;
    }
    __syncthreads();
    #pragma unroll
    for (int ks = 0; ks < 2; ++ks){
      const int s = (ks*4 + lk) ^ (lc & 7);
      bf16x8 af[2], bfr[6];
      #pragma unroll
      for (int mi = 0; mi < 2; ++mi){
        int row = w*32 + mi*16 + lc;
        af[mi] = *(const bf16x8*)&lds[row*64 + s*8];
      }
      #pragma unroll
      for (int nj = 0; nj < 6; ++nj){
        int row = nj*16 + lc;
        bfr[nj] = *(const bf16x8*)&lds[8192 + row*64 + s*8];
      }
      #pragma unroll
      for (int mi = 0; mi < 2; ++mi)
        #pragma unroll
        for (int nj = 0; nj < 6; ++nj)
          acc[mi][nj] = __builtin_amdgcn_mfma_f32_16x16x32_bf16(af[mi], bfr[nj], acc[mi][nj], 0,0,0);
    }
    __syncthreads();
  }

  // ---- epilogue: bias + x*tanh(s), coalesced store via per-wave LDS transpose ----
  {
    short* epx = &lds[w*2560];          // 32 rows x 40-short pitch
    short* epy = &lds[w*2560 + 1280];
    float bs[2], bx[2], by[2];
    #pragma unroll
    for (int f = 0; f < 2; ++f){
      int col = h0 + f*16 + lc;
      bs[f] = b1[col]; bx[f] = b1[512 + col]; by[f] = b1[1024 + col];
    }
    #pragma unroll
    for (int mi = 0; mi < 2; ++mi)
      #pragma unroll
      for (int f = 0; f < 2; ++f)
        #pragma unroll
        for (int j = 0; j < 4; ++j){
          float sv = acc[mi][0+f][j] + bs[f];
          float xv = (acc[mi][2+f][j] + bx[f]) * fast_tanh(sv);
          float yv = acc[mi][4+f][j] + by[f];
          int row = mi*16 + lk*4 + j;
          epx[row*40 + f*16 + lc] = (short)f2bf(xv);
          epy[row*40 + f*16 + lc] = (short)f2bf(yv);
        }
    __syncthreads();
    const int row = lw >> 1, half = lw & 1;
    const size_t gbase = (size_t)(m0 + w*32 + row)*HID + h0 + half*16;
    #pragma unroll
    for (int q = 0; q < 2; ++q){
      bf16x8 v = *(const bf16x8*)&epx[row*40 + half*16 + q*8];
      *(bf16x8*)&xh[gbase + q*8] = v;
    }
    #pragma unroll
    for (int q = 0; q < 2; ++q){
      bf16x8 v = *(const bf16x8*)&epy[row*40 + half*16 + q*8];
      *(bf16x8*)&yb[gbase + q*8] = v;
    }
  }
}

// ---------------- Attention v10 (round-18 best): 4 waves cooperate on one tile ----------------
__global__ __launch_bounds__(256)
void k_attn(const float* __restrict__ aw, const float* __restrict__ wts,
            const int* __restrict__ idxs,
            const u16* __restrict__ xh, const u16* __restrict__ yb,
            u16* __restrict__ zb)
{
  __shared__ short ldsb[6144 + 12288];   // kv bf16 [0,6144); aw fp32 (24KB)
  short* lKv = ldsb;
  float* lAw = (float*)&ldsb[6144];
  const int tid0 = threadIdx.x;
  const int w = tid0 >> 6, lane = tid0 & 63;
  const int bid = blockIdx.x;    // ((h*8+b)*64+n)
  const int h = bid >> 9;
  const int b = (bid >> 6) & 7;
  const int n = bid & 63;
  const int bh = n >> 3, bw = n & 7;

  // ---- 1. aw staging: 24 chunks of 1KB; wave w -> chunks i*4+w ----
  {
    const float* awt = aw + (size_t)bid * 6144;
    #pragma unroll
    for (int i = 0; i < 6; ++i){
      int c = i*4 + w;
      int s = c*64 + lane;                // dest 16B-slice (0..1535)
      int row = s / 24;
      int sir = s - row*24;
      int src = row*24 + (sir ^ (row & 7));
      gload_lds16(awt + src*4, (char*)lAw + (size_t)c*1024);
    }
  }

  // ---- 2. kv gather (cooperative): 48 pairs x 8 dg = 384 slots ----
  {
    const int dg = tid0 & 7;
    {
      int pair = tid0 >> 3;
      int t0 = pair*2;
      int pix = (bh*8 + (t0>>3))*64 + bw*8 + (t0&7);
      size_t r0 = (size_t)b*4096 + pix, r1 = r0 + 1;
      bf16x8 v0 = *(const bf16x8*)&xh[r0*HID + h*64 + dg*8];
      bf16x8 v1 = *(const bf16x8*)&xh[r1*HID + h*64 + dg*8];
      #pragma unroll
      for (int j = 0; j < 8; ++j){
        int d = dg*8 + j;
        int elem = (d*96 + t0) ^ (dg<<3);
        unsigned pk = (unsigned)(u16)v0[j] | ((unsigned)(u16)v1[j] << 16);
        *(unsigned*)&lKv[elem] = pk;
      }
    }
    if (tid0 < 128){
      int pr = tid0 >> 3;                 // 0..15
      int t0 = 64 + pr*2;
      int e = (b*64+n)*32 + pr*2;
      size_t r0 = (size_t)b*4096 + idxs[e];
      size_t r1 = (size_t)b*4096 + idxs[e+1];
      bf16x8 v0 = *(const bf16x8*)&xh[r0*HID + h*64 + dg*8];
      bf16x8 v1 = *(const bf16x8*)&xh[r1*HID + h*64 + dg*8];
      #pragma unroll
      for (int j = 0; j < 8; ++j){
        int d = dg*8 + j;
        int elem = (d*96 + t0) ^ (dg<<3);
        unsigned pk = (unsigned)(u16)v0[j] | ((unsigned)(u16)v1[j] << 16);
        *(unsigned*)&lKv[elem] = pk;
      }
    }
  }

  // ---- 3. wts (per wave) + y prefetch ----
  float wv[8];
  {
    const float* wp = wts + (size_t)(b*64+n)*32 + (lane>>4)*8;
    float4 a = *(const float4*)wp, c = *(const float4*)(wp+4);
    wv[0]=a.x; wv[1]=a.y; wv[2]=a.z; wv[3]=a.w;
    wv[4]=c.x; wv[5]=c.y; wv[6]=c.z; wv[7]=c.w;
  }
  bf16x8 yv0, yv1;
  const int yq = tid0 >> 2, yc = tid0 & 3;
  {
    int pix = (bh*8 + (yq>>3))*64 + bw*8 + (yq&7);
    const u16* yrow = yb + ((size_t)b*4096 + pix)*HID + h*64 + yc*16;
    yv0 = *(const bf16x8*)&yrow[0];
    yv1 = *(const bf16x8*)&yrow[8];
  }
  __syncthreads();   // all waves' kv writes + aw gloads visible

  // ---- 4. MFMA: wave w owns output rows [16w, 16w+16) ----
  const int lc = lane & 15, lk = lane >> 4;
  f32x4 acc[4] = {};
  #pragma unroll
  for (int ks = 0; ks < 3; ++ks){
    bf16x8 af;
    {
      int r = w*16 + lc;
      int sr = ks*8 + lk*2;
      int key = r & 7;
      float4 f0 = *(const float4*)&lAw[(r*24 + (sr ^ key))*4];
      float4 f1 = *(const float4*)&lAw[(r*24 + ((sr+1) ^ key))*4];
      float t[8] = {f0.x,f0.y,f0.z,f0.w,f1.x,f1.y,f1.z,f1.w};
      #pragma unroll
      for (int j = 0; j < 8; ++j){
        float v = (ks == 2) ? t[j]*wv[j] : t[j];
        af[j] = (short)f2bf(v);
      }
    }
    bf16x8 bv[4];
    #pragma unroll
    for (int nj = 0; nj < 4; ++nj){
      int d = nj*16 + lc;
      int idx = (d*96 + ks*32 + lk*8) ^ ((d>>3)<<3);
      bv[nj] = *(const bf16x8*)&lKv[idx];
    }
    #pragma unroll
    for (int nj = 0; nj < 4; ++nj)
      acc[nj] = __builtin_amdgcn_mfma_f32_16x16x32_bf16(af, bv[nj], acc[nj], 0,0,0);
  }
  __syncthreads();   // all kv reads done before y-transpose overwrites

  // ---- 5. y transpose through LDS: yl[q][d], pitch 72 ----
  *(bf16x8*)&lKv[yq*72 + yc*16    ] = yv0;
  *(bf16x8*)&lKv[yq*72 + yc*16 + 8] = yv1;

  // ---- 6. epilogue: z = out * y, v2 store pattern (rows 16w..16w+15) ----
  #pragma unroll
  for (int nj = 0; nj < 4; ++nj){
    int d = nj*16 + lc;
    size_t gcol = (size_t)h*64 + d;
    #pragma unroll
    for (int j = 0; j < 4; ++j){
      int q = w*16 + lk*4 + j;
      int pix = (bh*8 + (q>>3))*64 + bw*8 + (q&7);
      size_t r = (size_t)b*4096 + pix;
      float yvf = bf2f((u16)lKv[q*72 + d]);
      zb[r*HID + gcol] = f2bf(acc[nj][j] * yvf);
    }
  }
}

// ---------------- GEMM2 v6: BK=32 dbuf, counted vmcnt (unchanged, passing) ----------------
__global__ __launch_bounds__(256)
void k_gemm2(const u16* __restrict__ zb, const u16* __restrict__ w2b,
             const float* __restrict__ b2, float* __restrict__ out)
{
  __shared__ short lds[16384];  // 32KB: buf stride 8192 shorts (A 4096 + B 4096)
  const int tid = threadIdx.x;
  const int w = tid>>6, lw = tid&63;
  const int wm = w>>1, wn = w&1;
  const int bid = blockIdx.x;
  const int xcd = bid & 7, ii = bid >> 3;
  const int m0 = (xcd*32 + ii/3) * 128;
  const int n0 = (ii%3) * 128;
  const int lc = lw & 15, lk = lw >> 4;

  f32x4 acc[4][4] = {};

  const int sl_g = (lw & 3) ^ ((lw >> 3) & 3);
  const int rsub = lw >> 2;
  const u16* gsrc[4]; int ldst[4];
  #pragma unroll
  for (int i = 0; i < 4; ++i){
    int c = w*4 + i;
    if (c < 8){
      int r = c*16 + rsub;
      gsrc[i] = zb + (size_t)(m0+r)*HID + sl_g*8;
      ldst[i] = c*512;
    } else {
      int cb = c - 8;
      int r = cb*16 + rsub;
      gsrc[i] = w2b + (size_t)(n0+r)*HID + sl_g*8;
      ldst[i] = 4096 + cb*512;
    }
  }
  auto STAGE = [&](int buf, int kt){
    #pragma unroll
    for (int i = 0; i < 4; ++i)
      gload_lds16(gsrc[i] + kt*32, &lds[ldst[i] + buf*8192]);
  };
  const int skey = (lc >> 1) & 3;
  auto COMPUTE = [&](int buf){
    const short* pa = lds + buf*8192;
    const short* pb = lds + buf*8192 + 4096;
    bf16x8 af[4], bb[4];
    #pragma unroll
    for (int mi=0; mi<4; ++mi){
      int row = wm*64 + mi*16 + lc;
      af[mi] = *(const bf16x8*)&pa[row*32 + (lk ^ skey)*8];
    }
    #pragma unroll
    for (int nj=0; nj<4; ++nj){
      int row = wn*64 + nj*16 + lc;
      bb[nj] = *(const bf16x8*)&pb[row*32 + (lk ^ skey)*8];
    }
    #pragma unroll
    for (int mi=0; mi<4; ++mi)
      #pragma unroll
      for (int nj=0; nj<4; ++nj)
        acc[mi][nj] = __builtin_amdgcn_mfma_f32_16x16x32_bf16(af[mi], bb[nj], acc[mi][nj], 0,0,0);
  };

  STAGE(0, 0);
  #pragma unroll 1
  for (int kt = 0; kt < 16; ++kt){
    if (kt < 15){
      STAGE((kt+1)&1, kt+1);
      asm volatile("s_waitcnt vmcnt(4)" ::: "memory");
    } else {
      asm volatile("s_waitcnt vmcnt(0)" ::: "memory");
    }
    __builtin_amdgcn_sched_barrier(0);
    __builtin_amdgcn_s_barrier();
    COMPUTE(kt&1);
    __builtin_amdgcn_sched_barrier(0);
    __builtin_amdgcn_s_barrier();
  }

  const int lr4 = lk*4;
  #pragma unroll
  for (int nj=0; nj<4; ++nj){
    int col = n0 + wn*64 + nj*16 + lc;
    float bias = b2[col];
    #pragma unroll
    for (int mi=0; mi<4; ++mi){
      #pragma unroll
      for (int j=0; j<4; ++j){
        int row = m0 + wm*64 + mi*16 + lr4 + j;
        out[(size_t)row*CH + col] = acc[mi][nj][j] + bias;
      }
    }
  }
}

extern "C" void kernel_launch(void* const* d_in, const int* in_sizes, int n_in,
                              void* d_out, int out_size, void* d_ws, size_t ws_size,
                              hipStream_t stream) {
  const float* x   = (const float*)d_in[0];
  const float* aw  = (const float*)d_in[1];
  const float* wts = (const float*)d_in[2];
  const float* w1  = (const float*)d_in[3];
  const float* b1  = (const float*)d_in[4];
  const float* w2  = (const float*)d_in[5];
  const float* b2  = (const float*)d_in[6];
  const int*   idx = (const int*)d_in[7];
  float* out = (float*)d_out;

  char* ws = (char*)d_ws;
  u16* w1_bf = (u16*)(ws + 25165824);                   // 1179648
  u16* w2_bf = (u16*)(ws + 26345472);                   // 393216
  u16* xh_bf = (u16*)(ws + 26738688);                   // 33554432
  u16* y_bf  = (u16*)(ws + 60293120);                   // 33554432
  u16* z_bf  = (u16*)(ws + 93847552);                   // 33554432

  k_cvt2<<<768, 256, 0, stream>>>(w1, w1_bf, w2, w2_bf);

  k_gemm1<<<4096, 256, 0, stream>>>(x, w1_bf, b1, xh_bf, y_bf);
  k_attn<<<NHD*8*64, 256, 0, stream>>>(aw, wts, idx, xh_bf, y_bf, z_bf);
  k_gemm2<<<768, 256, 0, stream>>>(z_bf, w2_bf, b2, out);
}

// Round 21
// 137.354 us; speedup vs baseline: 1.0953x; 1.0953x over previous
//
#include <hip/hip_runtime.h>
#include <hip/hip_bf16.h>
#include <stdint.h>

#define CH   384
#define HID  512
#define NHD  8
#define MTOT 32768   // B*H*W tokens

typedef __attribute__((ext_vector_type(8))) short bf16x8;
typedef __attribute__((ext_vector_type(4))) float f32x4;
typedef unsigned short u16;

__device__ __forceinline__ float bf2f(u16 v){ return __uint_as_float(((unsigned)v)<<16); }
__device__ __forceinline__ u16 f2bf(float f){
  unsigned u = __float_as_uint(f);
  return (u16)((u + 0x7fffu + ((u>>16)&1u)) >> 16);
}
__device__ __forceinline__ float fast_tanh(float s){
  float e = __expf(2.f*s);
  return 1.f - 2.f*__builtin_amdgcn_rcpf(e + 1.f);
}
__device__ __forceinline__ void gload_lds16(const void* g, void* l){
  __builtin_amdgcn_global_load_lds((const __attribute__((address_space(1))) void*)g,
                                   (__attribute__((address_space(3))) void*)l, 16, 0, 0);
}

// ---------------- fused fp32 -> bf16 convert (x, W1, W2 in one launch) ----------------
#define CVT_N1 (MTOT*CH/4)        // 3145728 float4s
#define CVT_N2 (3*HID*CH/4)       // 147456
#define CVT_N3 (CH*HID/4)         // 49152
__global__ void k_cvt3(const float* __restrict__ x,  u16* __restrict__ xo,
                       const float* __restrict__ w1, u16* __restrict__ w1o,
                       const float* __restrict__ w2, u16* __restrict__ w2o){
  const int total = CVT_N1 + CVT_N2 + CVT_N3;
  int i = blockIdx.x*blockDim.x + threadIdx.x;
  int stride = gridDim.x*blockDim.x;
  for (; i < total; i += stride){
    const float4* src; ushort4* dst; int k;
    if (i < CVT_N1){ src = (const float4*)x;  dst = (ushort4*)xo;  k = i; }
    else if (i < CVT_N1 + CVT_N2){ src = (const float4*)w1; dst = (ushort4*)w1o; k = i - CVT_N1; }
    else { src = (const float4*)w2; dst = (ushort4*)w2o; k = i - CVT_N1 - CVT_N2; }
    float4 v = src[k];
    ushort4 o; o.x=f2bf(v.x); o.y=f2bf(v.y); o.z=f2bf(v.z); o.w=f2bf(v.w);
    dst[k] = o;
  }
}

// ---------------- GEMM1 v8 (proven 63.5us, epilogue barrier removed) ----------------
__global__ __launch_bounds__(256)
void k_gemm1(const u16* __restrict__ xb, const u16* __restrict__ w1b,
             const float* __restrict__ b1,
             u16* __restrict__ xh, u16* __restrict__ yb)
{
  __shared__ short lds[14336];  // A [0,8192)  B [8192,14336)  (28KB)
  const int tid = threadIdx.x;
  const int w = tid >> 6, lw = tid & 63;
  const int bid = blockIdx.x;
  const int xcd = bid & 7, ii = bid >> 3;
  const int m0 = (xcd*32 + (ii >> 4)) * 128;
  const int h0 = (ii & 15) * 32;
  const int lc = lw & 15, lk = lw >> 4;

  f32x4 acc[2][6] = {};   // [mi][seg*2+f]

  const int sl = (lw & 7) ^ (lw >> 3);
  const int rsub = lw >> 3;
  const u16* gsrc[7]; int ldst[7];
  #pragma unroll
  for (int i = 0; i < 7; ++i){
    int c = w*7 + i;
    if (c < 16){
      int r = c*8 + rsub;
      gsrc[i] = xb + (size_t)(m0 + r)*CH + sl*8;
      ldst[i] = c*512;
    } else {
      int rb = (c-16)*8 + rsub;                 // 0..95
      int grow = (rb >> 5)*HID + h0 + (rb & 31);
      gsrc[i] = w1b + (size_t)grow*CH + sl*8;
      ldst[i] = 8192 + (c-16)*512;
    }
  }

  #pragma unroll 1
  for (int kt = 0; kt < 6; ++kt){
    #pragma unroll
    for (int i = 0; i < 7; ++i)
      gload_lds16(gsrc[i] + kt*64, &lds[ldst[i]]);
    __syncthreads();
    #pragma unroll
    for (int ks = 0; ks < 2; ++ks){
      const int s = (ks*4 + lk) ^ (lc & 7);
      bf16x8 af[2], bfr[6];
      #pragma unroll
      for (int mi = 0; mi < 2; ++mi){
        int row = w*32 + mi*16 + lc;
        af[mi] = *(const bf16x8*)&lds[row*64 + s*8];
      }
      #pragma unroll
      for (int nj = 0; nj < 6; ++nj){
        int row = nj*16 + lc;
        bfr[nj] = *(const bf16x8*)&lds[8192 + row*64 + s*8];
      }
      #pragma unroll
      for (int mi = 0; mi < 2; ++mi)
        #pragma unroll
        for (int nj = 0; nj < 6; ++nj)
          acc[mi][nj] = __builtin_amdgcn_mfma_f32_16x16x32_bf16(af[mi], bfr[nj], acc[mi][nj], 0,0,0);
    }
    __syncthreads();
  }

  // ---- epilogue: per-wave LDS transpose (wave-private regions; no barrier needed) ----
  {
    short* epx = &lds[w*2560];          // 32 rows x 40-short pitch
    short* epy = &lds[w*2560 + 1280];
    float bs[2], bx[2], by[2];
    #pragma unroll
    for (int f = 0; f < 2; ++f){
      int col = h0 + f*16 + lc;
      bs[f] = b1[col]; bx[f] = b1[512 + col]; by[f] = b1[1024 + col];
    }
    #pragma unroll
    for (int mi = 0; mi < 2; ++mi)
      #pragma unroll
      for (int f = 0; f < 2; ++f)
        #pragma unroll
        for (int j = 0; j < 4; ++j){
          float sv = acc[mi][0+f][j] + bs[f];
          float xv = (acc[mi][2+f][j] + bx[f]) * fast_tanh(sv);
          float yv = acc[mi][4+f][j] + by[f];
          int row = mi*16 + lk*4 + j;
          epx[row*40 + f*16 + lc] = (short)f2bf(xv);
          epy[row*40 + f*16 + lc] = (short)f2bf(yv);
        }
    // same-wave ds_write -> ds_read: hardware-ordered, no __syncthreads
    const int row = lw >> 1, half = lw & 1;
    const size_t gbase = (size_t)(m0 + w*32 + row)*HID + h0 + half*16;
    #pragma unroll
    for (int q = 0; q < 2; ++q){
      bf16x8 v = *(const bf16x8*)&epx[row*40 + half*16 + q*8];
      *(bf16x8*)&xh[gbase + q*8] = v;
    }
    #pragma unroll
    for (int q = 0; q < 2; ++q){
      bf16x8 v = *(const bf16x8*)&epy[row*40 + half*16 + q*8];
      *(bf16x8*)&yb[gbase + q*8] = v;
    }
  }
}

// ---------------- Attention v10 (round-18 best): 4 waves cooperate on one tile ----------------
__global__ __launch_bounds__(256)
void k_attn(const float* __restrict__ aw, const float* __restrict__ wts,
            const int* __restrict__ idxs,
            const u16* __restrict__ xh, const u16* __restrict__ yb,
            u16* __restrict__ zb)
{
  __shared__ short ldsb[6144 + 12288];   // kv bf16 [0,6144); aw fp32 (24KB)
  short* lKv = ldsb;
  float* lAw = (float*)&ldsb[6144];
  const int tid0 = threadIdx.x;
  const int w = tid0 >> 6, lane = tid0 & 63;
  const int bid = blockIdx.x;    // ((h*8+b)*64+n)
  const int h = bid >> 9;
  const int b = (bid >> 6) & 7;
  const int n = bid & 63;
  const int bh = n >> 3, bw = n & 7;

  // ---- 1. aw staging: 24 chunks of 1KB; wave w -> chunks i*4+w ----
  {
    const float* awt = aw + (size_t)bid * 6144;
    #pragma unroll
    for (int i = 0; i < 6; ++i){
      int c = i*4 + w;
      int s = c*64 + lane;                // dest 16B-slice (0..1535)
      int row = s / 24;
      int sir = s - row*24;
      int src = row*24 + (sir ^ (row & 7));
      gload_lds16(awt + src*4, (char*)lAw + (size_t)c*1024);
    }
  }

  // ---- 2. kv gather (cooperative): 48 pairs x 8 dg = 384 slots ----
  {
    const int dg = tid0 & 7;
    {
      int pair = tid0 >> 3;
      int t0 = pair*2;
      int pix = (bh*8 + (t0>>3))*64 + bw*8 + (t0&7);
      size_t r0 = (size_t)b*4096 + pix, r1 = r0 + 1;
      bf16x8 v0 = *(const bf16x8*)&xh[r0*HID + h*64 + dg*8];
      bf16x8 v1 = *(const bf16x8*)&xh[r1*HID + h*64 + dg*8];
      #pragma unroll
      for (int j = 0; j < 8; ++j){
        int d = dg*8 + j;
        int elem = (d*96 + t0) ^ (dg<<3);
        unsigned pk = (unsigned)(u16)v0[j] | ((unsigned)(u16)v1[j] << 16);
        *(unsigned*)&lKv[elem] = pk;
      }
    }
    if (tid0 < 128){
      int pr = tid0 >> 3;                 // 0..15
      int t0 = 64 + pr*2;
      int e = (b*64+n)*32 + pr*2;
      size_t r0 = (size_t)b*4096 + idxs[e];
      size_t r1 = (size_t)b*4096 + idxs[e+1];
      bf16x8 v0 = *(const bf16x8*)&xh[r0*HID + h*64 + dg*8];
      bf16x8 v1 = *(const bf16x8*)&xh[r1*HID + h*64 + dg*8];
      #pragma unroll
      for (int j = 0; j < 8; ++j){
        int d = dg*8 + j;
        int elem = (d*96 + t0) ^ (dg<<3);
        unsigned pk = (unsigned)(u16)v0[j] | ((unsigned)(u16)v1[j] << 16);
        *(unsigned*)&lKv[elem] = pk;
      }
    }
  }

  // ---- 3. wts (per wave) + y prefetch ----
  float wv[8];
  {
    const float* wp = wts + (size_t)(b*64+n)*32 + (lane>>4)*8;
    float4 a = *(const float4*)wp, c = *(const float4*)(wp+4);
    wv[0]=a.x; wv[1]=a.y; wv[2]=a.z; wv[3]=a.w;
    wv[4]=c.x; wv[5]=c.y; wv[6]=c.z; wv[7]=c.w;
  }
  bf16x8 yv0, yv1;
  const int yq = tid0 >> 2, yc = tid0 & 3;
  {
    int pix = (bh*8 + (yq>>3))*64 + bw*8 + (yq&7);
    const u16* yrow = yb + ((size_t)b*4096 + pix)*HID + h*64 + yc*16;
    yv0 = *(const bf16x8*)&yrow[0];
    yv1 = *(const bf16x8*)&yrow[8];
  }
  __syncthreads();   // all waves' kv writes + aw gloads visible

  // ---- 4. MFMA: wave w owns output rows [16w, 16w+16) ----
  const int lc = lane & 15, lk = lane >> 4;
  f32x4 acc[4] = {};
  #pragma unroll
  for (int ks = 0; ks < 3; ++ks){
    bf16x8 af;
    {
      int r = w*16 + lc;
      int sr = ks*8 + lk*2;
      int key = r & 7;
      float4 f0 = *(const float4*)&lAw[(r*24 + (sr ^ key))*4];
      float4 f1 = *(const float4*)&lAw[(r*24 + ((sr+1) ^ key))*4];
      float t[8] = {f0.x,f0.y,f0.z,f0.w,f1.x,f1.y,f1.z,f1.w};
      #pragma unroll
      for (int j = 0; j < 8; ++j){
        float v = (ks == 2) ? t[j]*wv[j] : t[j];
        af[j] = (short)f2bf(v);
      }
    }
    bf16x8 bv[4];
    #pragma unroll
    for (int nj = 0; nj < 4; ++nj){
      int d = nj*16 + lc;
      int idx = (d*96 + ks*32 + lk*8) ^ ((d>>3)<<3);
      bv[nj] = *(const bf16x8*)&lKv[idx];
    }
    #pragma unroll
    for (int nj = 0; nj < 4; ++nj)
      acc[nj] = __builtin_amdgcn_mfma_f32_16x16x32_bf16(af, bv[nj], acc[nj], 0,0,0);
  }
  __syncthreads();   // all kv reads done before y-transpose overwrites

  // ---- 5. y transpose through LDS: yl[q][d], pitch 72 ----
  *(bf16x8*)&lKv[yq*72 + yc*16    ] = yv0;
  *(bf16x8*)&lKv[yq*72 + yc*16 + 8] = yv1;

  // ---- 6. epilogue: z = out * y, v2 store pattern (rows 16w..16w+15) ----
  #pragma unroll
  for (int nj = 0; nj < 4; ++nj){
    int d = nj*16 + lc;
    size_t gcol = (size_t)h*64 + d;
    #pragma unroll
    for (int j = 0; j < 4; ++j){
      int q = w*16 + lk*4 + j;
      int pix = (bh*8 + (q>>3))*64 + bw*8 + (q&7);
      size_t r = (size_t)b*4096 + pix;
      float yvf = bf2f((u16)lKv[q*72 + d]);
      zb[r*HID + gcol] = f2bf(acc[nj][j] * yvf);
    }
  }
}

// ---------------- GEMM2 v7: gemm1-v8 pattern (BK=64, single 32KB buffer, 8 kt) ----------------
__global__ __launch_bounds__(256)
void k_gemm2(const u16* __restrict__ zb, const u16* __restrict__ w2b,
             const float* __restrict__ b2, float* __restrict__ out)
{
  __shared__ short lds[16384];  // A [0,8192)  B [8192,16384)  (32KB)
  const int tid = threadIdx.x;
  const int w = tid>>6, lw = tid&63;
  const int wm = w>>1, wn = w&1;
  const int bid = blockIdx.x;
  const int xcd = bid & 7, ii = bid >> 3;
  const int m0 = (xcd*32 + ii/3) * 128;
  const int n0 = (ii%3) * 128;
  const int lc = lw & 15, lk = lw >> 4;

  f32x4 acc[4][4] = {};

  // staging: 32 chunks (16 A + 16 B) of 8 rows x 128B; wave w -> 8 chunks.
  const int sl = (lw & 7) ^ (lw >> 3);
  const int rsub = lw >> 3;
  const u16* gsrc[8]; int ldst[8];
  #pragma unroll
  for (int i = 0; i < 8; ++i){
    int c = w*8 + i;
    if (c < 16){
      int r = c*8 + rsub;
      gsrc[i] = zb + (size_t)(m0 + r)*HID + sl*8;
      ldst[i] = c*512;
    } else {
      int cb = c - 16;
      int r = cb*8 + rsub;
      gsrc[i] = w2b + (size_t)(n0 + r)*HID + sl*8;
      ldst[i] = 8192 + cb*512;
    }
  }

  #pragma unroll 1
  for (int kt = 0; kt < 8; ++kt){
    #pragma unroll
    for (int i = 0; i < 8; ++i)
      gload_lds16(gsrc[i] + kt*64, &lds[ldst[i]]);
    __syncthreads();
    #pragma unroll
    for (int ks = 0; ks < 2; ++ks){
      const int s = (ks*4 + lk) ^ (lc & 7);
      bf16x8 af[4], bb[4];
      #pragma unroll
      for (int mi = 0; mi < 4; ++mi){
        int row = wm*64 + mi*16 + lc;
        af[mi] = *(const bf16x8*)&lds[row*64 + s*8];
      }
      #pragma unroll
      for (int nj = 0; nj < 4; ++nj){
        int row = wn*64 + nj*16 + lc;
        bb[nj] = *(const bf16x8*)&lds[8192 + row*64 + s*8];
      }
      #pragma unroll
      for (int mi = 0; mi < 4; ++mi)
        #pragma unroll
        for (int nj = 0; nj < 4; ++nj)
          acc[mi][nj] = __builtin_amdgcn_mfma_f32_16x16x32_bf16(af[mi], bb[nj], acc[mi][nj], 0,0,0);
    }
    __syncthreads();
  }

  const int lr4 = lk*4;
  #pragma unroll
  for (int nj = 0; nj < 4; ++nj){
    int col = n0 + wn*64 + nj*16 + lc;
    float bias = b2[col];
    #pragma unroll
    for (int mi = 0; mi < 4; ++mi){
      #pragma unroll
      for (int j = 0; j < 4; ++j){
        int row = m0 + wm*64 + mi*16 + lr4 + j;
        out[(size_t)row*CH + col] = acc[mi][nj][j] + bias;
      }
    }
  }
}

extern "C" void kernel_launch(void* const* d_in, const int* in_sizes, int n_in,
                              void* d_out, int out_size, void* d_ws, size_t ws_size,
                              hipStream_t stream) {
  const float* x   = (const float*)d_in[0];
  const float* aw  = (const float*)d_in[1];
  const float* wts = (const float*)d_in[2];
  const float* w1  = (const float*)d_in[3];
  const float* b1  = (const float*)d_in[4];
  const float* w2  = (const float*)d_in[5];
  const float* b2  = (const float*)d_in[6];
  const int*   idx = (const int*)d_in[7];
  float* out = (float*)d_out;

  char* ws = (char*)d_ws;
  u16* x_bf  = (u16*)(ws);                              // 25165824
  u16* w1_bf = (u16*)(ws + 25165824);                   // 1179648
  u16* w2_bf = (u16*)(ws + 26345472);                   // 393216
  u16* xh_bf = (u16*)(ws + 26738688);                   // 33554432
  u16* y_bf  = (u16*)(ws + 60293120);                   // 33554432
  u16* z_bf  = (u16*)(ws + 93847552);                   // 33554432

  k_cvt3<<<2048, 256, 0, stream>>>(x, x_bf, w1, w1_bf, w2, w2_bf);

  k_gemm1<<<4096, 256, 0, stream>>>(x_bf, w1_bf, b1, xh_bf, y_bf);
  k_attn<<<NHD*8*64, 256, 0, stream>>>(aw, wts, idx, xh_bf, y_bf, z_bf);
  k_gemm2<<<768, 256, 0, stream>>>(z_bf, w2_bf, b2, out);
}

// Round 22
// 134.992 us; speedup vs baseline: 1.1145x; 1.0175x over previous
//
#include <hip/hip_runtime.h>
#include <hip/hip_bf16.h>
#include <stdint.h>

#define CH   384
#define HID  512
#define NHD  8
#define MTOT 32768   // B*H*W tokens

typedef __attribute__((ext_vector_type(8))) short bf16x8;
typedef __attribute__((ext_vector_type(4))) float f32x4;
typedef unsigned short u16;

__device__ __forceinline__ float bf2f(u16 v){ return __uint_as_float(((unsigned)v)<<16); }
__device__ __forceinline__ u16 f2bf(float f){
  unsigned u = __float_as_uint(f);
  return (u16)((u + 0x7fffu + ((u>>16)&1u)) >> 16);
}
__device__ __forceinline__ float fast_tanh(float s){
  float e = __expf(2.f*s);
  return 1.f - 2.f*__builtin_amdgcn_rcpf(e + 1.f);
}
__device__ __forceinline__ void gload_lds16(const void* g, void* l){
  __builtin_amdgcn_global_load_lds((const __attribute__((address_space(1))) void*)g,
                                   (__attribute__((address_space(3))) void*)l, 16, 0, 0);
}

// ---------------- fused fp32 -> bf16 convert (x, W1, W2 in one launch) ----------------
#define CVT_N1 (MTOT*CH/4)        // 3145728 float4s
#define CVT_N2 (3*HID*CH/4)       // 147456
#define CVT_N3 (CH*HID/4)         // 49152
__global__ void k_cvt3(const float* __restrict__ x,  u16* __restrict__ xo,
                       const float* __restrict__ w1, u16* __restrict__ w1o,
                       const float* __restrict__ w2, u16* __restrict__ w2o){
  const int total = CVT_N1 + CVT_N2 + CVT_N3;
  int i = blockIdx.x*blockDim.x + threadIdx.x;
  int stride = gridDim.x*blockDim.x;
  for (; i < total; i += stride){
    const float4* src; ushort4* dst; int k;
    if (i < CVT_N1){ src = (const float4*)x;  dst = (ushort4*)xo;  k = i; }
    else if (i < CVT_N1 + CVT_N2){ src = (const float4*)w1; dst = (ushort4*)w1o; k = i - CVT_N1; }
    else { src = (const float4*)w2; dst = (ushort4*)w2o; k = i - CVT_N1 - CVT_N2; }
    float4 v = src[k];
    ushort4 o; o.x=f2bf(v.x); o.y=f2bf(v.y); o.z=f2bf(v.z); o.w=f2bf(v.w);
    dst[k] = o;
  }
}

// ---------------- GEMM1 v8 (proven 63.2us, barrier-free epilogue) ----------------
__global__ __launch_bounds__(256)
void k_gemm1(const u16* __restrict__ xb, const u16* __restrict__ w1b,
             const float* __restrict__ b1,
             u16* __restrict__ xh, u16* __restrict__ yb)
{
  __shared__ short lds[14336];  // A [0,8192)  B [8192,14336)  (28KB)
  const int tid = threadIdx.x;
  const int w = tid >> 6, lw = tid & 63;
  const int bid = blockIdx.x;
  const int xcd = bid & 7, ii = bid >> 3;
  const int m0 = (xcd*32 + (ii >> 4)) * 128;
  const int h0 = (ii & 15) * 32;
  const int lc = lw & 15, lk = lw >> 4;

  f32x4 acc[2][6] = {};   // [mi][seg*2+f]

  const int sl = (lw & 7) ^ (lw >> 3);
  const int rsub = lw >> 3;
  const u16* gsrc[7]; int ldst[7];
  #pragma unroll
  for (int i = 0; i < 7; ++i){
    int c = w*7 + i;
    if (c < 16){
      int r = c*8 + rsub;
      gsrc[i] = xb + (size_t)(m0 + r)*CH + sl*8;
      ldst[i] = c*512;
    } else {
      int rb = (c-16)*8 + rsub;                 // 0..95
      int grow = (rb >> 5)*HID + h0 + (rb & 31);
      gsrc[i] = w1b + (size_t)grow*CH + sl*8;
      ldst[i] = 8192 + (c-16)*512;
    }
  }

  #pragma unroll 1
  for (int kt = 0; kt < 6; ++kt){
    #pragma unroll
    for (int i = 0; i < 7; ++i)
      gload_lds16(gsrc[i] + kt*64, &lds[ldst[i]]);
    __syncthreads();
    #pragma unroll
    for (int ks = 0; ks < 2; ++ks){
      const int s = (ks*4 + lk) ^ (lc & 7);
      bf16x8 af[2], bfr[6];
      #pragma unroll
      for (int mi = 0; mi < 2; ++mi){
        int row = w*32 + mi*16 + lc;
        af[mi] = *(const bf16x8*)&lds[row*64 + s*8];
      }
      #pragma unroll
      for (int nj = 0; nj < 6; ++nj){
        int row = nj*16 + lc;
        bfr[nj] = *(const bf16x8*)&lds[8192 + row*64 + s*8];
      }
      #pragma unroll
      for (int mi = 0; mi < 2; ++mi)
        #pragma unroll
        for (int nj = 0; nj < 6; ++nj)
          acc[mi][nj] = __builtin_amdgcn_mfma_f32_16x16x32_bf16(af[mi], bfr[nj], acc[mi][nj], 0,0,0);
    }
    __syncthreads();
  }

  // ---- epilogue: per-wave LDS transpose (wave-private; same-wave ds order) ----
  {
    short* epx = &lds[w*2560];          // 32 rows x 40-short pitch
    short* epy = &lds[w*2560 + 1280];
    float bs[2], bx[2], by[2];
    #pragma unroll
    for (int f = 0; f < 2; ++f){
      int col = h0 + f*16 + lc;
      bs[f] = b1[col]; bx[f] = b1[512 + col]; by[f] = b1[1024 + col];
    }
    #pragma unroll
    for (int mi = 0; mi < 2; ++mi)
      #pragma unroll
      for (int f = 0; f < 2; ++f)
        #pragma unroll
        for (int j = 0; j < 4; ++j){
          float sv = acc[mi][0+f][j] + bs[f];
          float xv = (acc[mi][2+f][j] + bx[f]) * fast_tanh(sv);
          float yv = acc[mi][4+f][j] + by[f];
          int row = mi*16 + lk*4 + j;
          epx[row*40 + f*16 + lc] = (short)f2bf(xv);
          epy[row*40 + f*16 + lc] = (short)f2bf(yv);
        }
    const int row = lw >> 1, half = lw & 1;
    const size_t gbase = (size_t)(m0 + w*32 + row)*HID + h0 + half*16;
    #pragma unroll
    for (int q = 0; q < 2; ++q){
      bf16x8 v = *(const bf16x8*)&epx[row*40 + half*16 + q*8];
      *(bf16x8*)&xh[gbase + q*8] = v;
    }
    #pragma unroll
    for (int q = 0; q < 2; ++q){
      bf16x8 v = *(const bf16x8*)&epy[row*40 + half*16 + q*8];
      *(bf16x8*)&yb[gbase + q*8] = v;
    }
  }
}

// ---------------- Attention v10 (round-18 best, ~33us): 4 waves cooperate on one tile ----------------
__global__ __launch_bounds__(256)
void k_attn(const float* __restrict__ aw, const float* __restrict__ wts,
            const int* __restrict__ idxs,
            const u16* __restrict__ xh, const u16* __restrict__ yb,
            u16* __restrict__ zb)
{
  __shared__ short ldsb[6144 + 12288];   // kv bf16 [0,6144); aw fp32 (24KB)
  short* lKv = ldsb;
  float* lAw = (float*)&ldsb[6144];
  const int tid0 = threadIdx.x;
  const int w = tid0 >> 6, lane = tid0 & 63;
  const int bid = blockIdx.x;    // ((h*8+b)*64+n)
  const int h = bid >> 9;
  const int b = (bid >> 6) & 7;
  const int n = bid & 63;
  const int bh = n >> 3, bw = n & 7;

  // ---- 1. aw staging: 24 chunks of 1KB; wave w -> chunks i*4+w ----
  {
    const float* awt = aw + (size_t)bid * 6144;
    #pragma unroll
    for (int i = 0; i < 6; ++i){
      int c = i*4 + w;
      int s = c*64 + lane;                // dest 16B-slice (0..1535)
      int row = s / 24;
      int sir = s - row*24;
      int src = row*24 + (sir ^ (row & 7));
      gload_lds16(awt + src*4, (char*)lAw + (size_t)c*1024);
    }
  }

  // ---- 2. kv gather (cooperative): 48 pairs x 8 dg = 384 slots ----
  {
    const int dg = tid0 & 7;
    {
      int pair = tid0 >> 3;
      int t0 = pair*2;
      int pix = (bh*8 + (t0>>3))*64 + bw*8 + (t0&7);
      size_t r0 = (size_t)b*4096 + pix, r1 = r0 + 1;
      bf16x8 v0 = *(const bf16x8*)&xh[r0*HID + h*64 + dg*8];
      bf16x8 v1 = *(const bf16x8*)&xh[r1*HID + h*64 + dg*8];
      #pragma unroll
      for (int j = 0; j < 8; ++j){
        int d = dg*8 + j;
        int elem = (d*96 + t0) ^ (dg<<3);
        unsigned pk = (unsigned)(u16)v0[j] | ((unsigned)(u16)v1[j] << 16);
        *(unsigned*)&lKv[elem] = pk;
      }
    }
    if (tid0 < 128){
      int pr = tid0 >> 3;                 // 0..15
      int t0 = 64 + pr*2;
      int e = (b*64+n)*32 + pr*2;
      size_t r0 = (size_t)b*4096 + idxs[e];
      size_t r1 = (size_t)b*4096 + idxs[e+1];
      bf16x8 v0 = *(const bf16x8*)&xh[r0*HID + h*64 + dg*8];
      bf16x8 v1 = *(const bf16x8*)&xh[r1*HID + h*64 + dg*8];
      #pragma unroll
      for (int j = 0; j < 8; ++j){
        int d = dg*8 + j;
        int elem = (d*96 + t0) ^ (dg<<3);
        unsigned pk = (unsigned)(u16)v0[j] | ((unsigned)(u16)v1[j] << 16);
        *(unsigned*)&lKv[elem] = pk;
      }
    }
  }

  // ---- 3. wts (per wave) + y prefetch ----
  float wv[8];
  {
    const float* wp = wts + (size_t)(b*64+n)*32 + (lane>>4)*8;
    float4 a = *(const float4*)wp, c = *(const float4*)(wp+4);
    wv[0]=a.x; wv[1]=a.y; wv[2]=a.z; wv[3]=a.w;
    wv[4]=c.x; wv[5]=c.y; wv[6]=c.z; wv[7]=c.w;
  }
  bf16x8 yv0, yv1;
  const int yq = tid0 >> 2, yc = tid0 & 3;
  {
    int pix = (bh*8 + (yq>>3))*64 + bw*8 + (yq&7);
    const u16* yrow = yb + ((size_t)b*4096 + pix)*HID + h*64 + yc*16;
    yv0 = *(const bf16x8*)&yrow[0];
    yv1 = *(const bf16x8*)&yrow[8];
  }
  __syncthreads();   // all waves' kv writes + aw gloads visible

  // ---- 4. MFMA: wave w owns output rows [16w, 16w+16) ----
  const int lc = lane & 15, lk = lane >> 4;
  f32x4 acc[4] = {};
  #pragma unroll
  for (int ks = 0; ks < 3; ++ks){
    bf16x8 af;
    {
      int r = w*16 + lc;
      int sr = ks*8 + lk*2;
      int key = r & 7;
      float4 f0 = *(const float4*)&lAw[(r*24 + (sr ^ key))*4];
      float4 f1 = *(const float4*)&lAw[(r*24 + ((sr+1) ^ key))*4];
      float t[8] = {f0.x,f0.y,f0.z,f0.w,f1.x,f1.y,f1.z,f1.w};
      #pragma unroll
      for (int j = 0; j < 8; ++j){
        float v = (ks == 2) ? t[j]*wv[j] : t[j];
        af[j] = (short)f2bf(v);
      }
    }
    bf16x8 bv[4];
    #pragma unroll
    for (int nj = 0; nj < 4; ++nj){
      int d = nj*16 + lc;
      int idx = (d*96 + ks*32 + lk*8) ^ ((d>>3)<<3);
      bv[nj] = *(const bf16x8*)&lKv[idx];
    }
    #pragma unroll
    for (int nj = 0; nj < 4; ++nj)
      acc[nj] = __builtin_amdgcn_mfma_f32_16x16x32_bf16(af, bv[nj], acc[nj], 0,0,0);
  }
  __syncthreads();   // all kv reads done before y-transpose overwrites

  // ---- 5. y transpose through LDS: yl[q][d], pitch 72 ----
  *(bf16x8*)&lKv[yq*72 + yc*16    ] = yv0;
  *(bf16x8*)&lKv[yq*72 + yc*16 + 8] = yv1;

  // ---- 6. epilogue: z = out * y, v2 store pattern (rows 16w..16w+15) ----
  #pragma unroll
  for (int nj = 0; nj < 4; ++nj){
    int d = nj*16 + lc;
    size_t gcol = (size_t)h*64 + d;
    #pragma unroll
    for (int j = 0; j < 4; ++j){
      int q = w*16 + lk*4 + j;
      int pix = (bh*8 + (q>>3))*64 + bw*8 + (q&7);
      size_t r = (size_t)b*4096 + pix;
      float yvf = bf2f((u16)lKv[q*72 + d]);
      zb[r*HID + gcol] = f2bf(acc[nj][j] * yvf);
    }
  }
}

// ---------------- GEMM2 v6 (round-18 best): BK=32 dbuf, counted vmcnt ----------------
__global__ __launch_bounds__(256)
void k_gemm2(const u16* __restrict__ zb, const u16* __restrict__ w2b,
             const float* __restrict__ b2, float* __restrict__ out)
{
  __shared__ short lds[16384];  // 32KB: buf stride 8192 shorts (A 4096 + B 4096)
  const int tid = threadIdx.x;
  const int w = tid>>6, lw = tid&63;
  const int wm = w>>1, wn = w&1;
  const int bid = blockIdx.x;
  const int xcd = bid & 7, ii = bid >> 3;
  const int m0 = (xcd*32 + ii/3) * 128;
  const int n0 = (ii%3) * 128;
  const int lc = lw & 15, lk = lw >> 4;

  f32x4 acc[4][4] = {};

  const int sl_g = (lw & 3) ^ ((lw >> 3) & 3);
  const int rsub = lw >> 2;
  const u16* gsrc[4]; int ldst[4];
  #pragma unroll
  for (int i = 0; i < 4; ++i){
    int c = w*4 + i;
    if (c < 8){
      int r = c*16 + rsub;
      gsrc[i] = zb + (size_t)(m0+r)*HID + sl_g*8;
      ldst[i] = c*512;
    } else {
      int cb = c - 8;
      int r = cb*16 + rsub;
      gsrc[i] = w2b + (size_t)(n0+r)*HID + sl_g*8;
      ldst[i] = 4096 + cb*512;
    }
  }
  auto STAGE = [&](int buf, int kt){
    #pragma unroll
    for (int i = 0; i < 4; ++i)
      gload_lds16(gsrc[i] + kt*32, &lds[ldst[i] + buf*8192]);
  };
  const int skey = (lc >> 1) & 3;
  auto COMPUTE = [&](int buf){
    const short* pa = lds + buf*8192;
    const short* pb = lds + buf*8192 + 4096;
    bf16x8 af[4], bb[4];
    #pragma unroll
    for (int mi=0; mi<4; ++mi){
      int row = wm*64 + mi*16 + lc;
      af[mi] = *(const bf16x8*)&pa[row*32 + (lk ^ skey)*8];
    }
    #pragma unroll
    for (int nj=0; nj<4; ++nj){
      int row = wn*64 + nj*16 + lc;
      bb[nj] = *(const bf16x8*)&pb[row*32 + (lk ^ skey)*8];
    }
    #pragma unroll
    for (int mi=0; mi<4; ++mi)
      #pragma unroll
      for (int nj=0; nj<4; ++nj)
        acc[mi][nj] = __builtin_amdgcn_mfma_f32_16x16x32_bf16(af[mi], bb[nj], acc[mi][nj], 0,0,0);
  };

  STAGE(0, 0);
  #pragma unroll 1
  for (int kt = 0; kt < 16; ++kt){
    if (kt < 15){
      STAGE((kt+1)&1, kt+1);
      asm volatile("s_waitcnt vmcnt(4)" ::: "memory");
    } else {
      asm volatile("s_waitcnt vmcnt(0)" ::: "memory");
    }
    __builtin_amdgcn_sched_barrier(0);
    __builtin_amdgcn_s_barrier();
    COMPUTE(kt&1);
    __builtin_amdgcn_sched_barrier(0);
    __builtin_amdgcn_s_barrier();
  }

  const int lr4 = lk*4;
  #pragma unroll
  for (int nj=0; nj<4; ++nj){
    int col = n0 + wn*64 + nj*16 + lc;
    float bias = b2[col];
    #pragma unroll
    for (int mi=0; mi<4; ++mi){
      #pragma unroll
      for (int j=0; j<4; ++j){
        int row = m0 + wm*64 + mi*16 + lr4 + j;
        out[(size_t)row*CH + col] = acc[mi][nj][j] + bias;
      }
    }
  }
}

extern "C" void kernel_launch(void* const* d_in, const int* in_sizes, int n_in,
                              void* d_out, int out_size, void* d_ws, size_t ws_size,
                              hipStream_t stream) {
  const float* x   = (const float*)d_in[0];
  const float* aw  = (const float*)d_in[1];
  const float* wts = (const float*)d_in[2];
  const float* w1  = (const float*)d_in[3];
  const float* b1  = (const float*)d_in[4];
  const float* w2  = (const float*)d_in[5];
  const float* b2  = (const float*)d_in[6];
  const int*   idx = (const int*)d_in[7];
  float* out = (float*)d_out;

  char* ws = (char*)d_ws;
  u16* x_bf  = (u16*)(ws);                              // 25165824
  u16* w1_bf = (u16*)(ws + 25165824);                   // 1179648
  u16* w2_bf = (u16*)(ws + 26345472);                   // 393216
  u16* xh_bf = (u16*)(ws + 26738688);                   // 33554432
  u16* y_bf  = (u16*)(ws + 60293120);                   // 33554432
  u16* z_bf  = (u16*)(ws + 93847552);                   // 33554432

  k_cvt3<<<2048, 256, 0, stream>>>(x, x_bf, w1, w1_bf, w2, w2_bf);

  k_gemm1<<<4096, 256, 0, stream>>>(x_bf, w1_bf, b1, xh_bf, y_bf);
  k_attn<<<NHD*8*64, 256, 0, stream>>>(aw, wts, idx, xh_bf, y_bf, z_bf);
  k_gemm2<<<768, 256, 0, stream>>>(z_bf, w2_bf, b2, out);
}